// Round 17
// baseline (126.617 us; speedup 1.0000x reference)
//
#include <hip/hip_runtime.h>

// out[n,k] = d[k] + sum_{ji,c} Bmat[k*49+ji][c] * bilinear_ji(proj[n,c,:,:])
// Bmat = WH·(w3·w2·w1); boxes constant -> pipeline fully linear in proj.
//
// k_mainf v2: block = (channel-group g, 16 n). Bmat values per thread are
// chunk-invariant -> 40 regs preloaded once; compute phase has ZERO global
// loads. lgkm-only barriers (raw s_barrier) keep prefetched proj loads alive
// across chunk boundaries; 2-deep prefetch (A/B reg sets, 2-unrolled loop).
//
// ws layout (floats):
//   WH    [490][512]   off 0
//   Y     [512][512]   off 250880
//   T1    [490][512]   off 513024
//   Bmat  [490][512]   off 763904
//   u2    [512]        off 1014784
//   vv    [512]        off 1015296
//   dpart [10][8]      off 1015808
//   part  [512*32*4][10] off 1015888  (2.6 MB)

#define CHW4 25088   // float4 per proj row
#define STEP 1.8571428571428572f  // 13/7

#define BAR() do { \
    __builtin_amdgcn_sched_barrier(0); \
    asm volatile("s_waitcnt lgkmcnt(0)" ::: "memory"); \
    __builtin_amdgcn_s_barrier(); \
    __builtin_amdgcn_sched_barrier(0); \
} while (0)

// ---------- prep level 1: WH transpose (blocks 0..489) + u2=b2+w2*b1 (490..553)
__global__ __launch_bounds__(512) void k_prep1(
    const float* __restrict__ w_note, const float* __restrict__ w_reg,
    const float* __restrict__ w2, const float* __restrict__ b1,
    const float* __restrict__ b2,
    float* __restrict__ WH, float* __restrict__ u2) {
    int blk = blockIdx.x;
    int tid = threadIdx.x;
    if (blk < 490) {
        int k = blk / 49, ji = blk % 49;
        const float* wh = (k < 2) ? (w_note + k * 25088) : (w_reg + (k - 2) * 25088);
        WH[(size_t)blk * 512 + tid] = wh[tid * 49 + ji];
    } else {
        int wv = tid >> 6, lane = tid & 63;
        int o = (blk - 490) * 8 + wv;
        float s = 0.f;
        #pragma unroll
        for (int r = 0; r < 8; ++r) s += w2[(size_t)o * 512 + lane + r * 64] * b1[lane + r * 64];
        for (int off = 32; off; off >>= 1) s += __shfl_down(s, off);
        if (lane == 0) u2[o] = b2[o] + s;
    }
}

// ---------- prep level 2: {Y=w2*w1 | T1=WH*w3} (0..511) + vv=b3+w3*u2 (512..639)
__global__ __launch_bounds__(256) void k_prep2(
    const float* __restrict__ w1, const float* __restrict__ w2,
    const float* __restrict__ w3, const float* __restrict__ WH,
    const float* __restrict__ u2, const float* __restrict__ b3,
    float* __restrict__ Y, float* __restrict__ T1, float* __restrict__ vv) {
    int blk = blockIdx.x;
    int tid = threadIdx.x;
    if (blk < 512) {
        __shared__ float As[32][36];
        __shared__ float Bs[32][36];
        const float* A; const float* B; float* C; int M;
        if (blk < 256) { A = w2; B = w1; C = Y;  M = 512; }
        else           { A = WH; B = w3; C = T1; M = 490; }
        int t = blk & 255;
        int bx = t & 15, by = t >> 4;
        int lr = tid >> 3, lc = (tid & 7) << 2;
        int tx = tid & 15, ty = tid >> 4;
        float a00 = 0.f, a01 = 0.f, a10 = 0.f, a11 = 0.f;
        for (int kc = 0; kc < 512; kc += 32) {
            int gr = by * 32 + lr;
            float4 av = make_float4(0.f, 0.f, 0.f, 0.f);
            if (gr < M) av = *(const float4*)&A[(size_t)gr * 512 + kc + lc];
            *(float4*)&As[lr][lc] = av;
            *(float4*)&Bs[lr][lc] = *(const float4*)&B[(size_t)(kc + lr) * 512 + bx * 32 + lc];
            __syncthreads();
            #pragma unroll
            for (int kk = 0; kk < 32; ++kk) {
                float b0 = Bs[kk][tx * 2], b1v = Bs[kk][tx * 2 + 1];
                float x0 = As[ty * 2][kk], x1 = As[ty * 2 + 1][kk];
                a00 += x0 * b0; a01 += x0 * b1v;
                a10 += x1 * b0; a11 += x1 * b1v;
            }
            __syncthreads();
        }
        int r0 = by * 32 + ty * 2, c0 = bx * 32 + tx * 2;
        if (r0 < M)     { C[(size_t)r0 * 512 + c0] = a00; C[(size_t)r0 * 512 + c0 + 1] = a01; }
        if (r0 + 1 < M) { C[(size_t)(r0 + 1) * 512 + c0] = a10; C[(size_t)(r0 + 1) * 512 + c0 + 1] = a11; }
    } else {
        int wv = tid >> 6, lane = tid & 63;
        int o = (blk - 512) * 4 + wv;
        float s = 0.f;
        #pragma unroll
        for (int r = 0; r < 8; ++r) s += w3[(size_t)o * 512 + lane + r * 64] * u2[lane + r * 64];
        for (int off = 32; off; off >>= 1) s += __shfl_down(s, off);
        if (lane == 0) vv[o] = b3[o] + s;
    }
}

// ---------- prep level 3: Bmat=T1*Y (0..255) + dpart (256..335)
__global__ __launch_bounds__(256) void k_prep3(
    const float* __restrict__ T1, const float* __restrict__ Y,
    const float* __restrict__ w_note, const float* __restrict__ w_reg,
    const float* __restrict__ vv,
    float* __restrict__ Bmat, float* __restrict__ dpart) {
    int blk = blockIdx.x;
    int tid = threadIdx.x;
    if (blk < 256) {
        __shared__ float As[32][36];
        __shared__ float Bs[32][36];
        int bx = blk & 15, by = blk >> 4;
        int lr = tid >> 3, lc = (tid & 7) << 2;
        int tx = tid & 15, ty = tid >> 4;
        int gr = by * 32 + lr;
        float a00 = 0.f, a01 = 0.f, a10 = 0.f, a11 = 0.f;
        for (int kc = 0; kc < 512; kc += 32) {
            float4 av = make_float4(0.f, 0.f, 0.f, 0.f);
            if (gr < 490) av = *(const float4*)&T1[(size_t)gr * 512 + kc + lc];
            *(float4*)&As[lr][lc] = av;
            *(float4*)&Bs[lr][lc] = *(const float4*)&Y[(size_t)(kc + lr) * 512 + bx * 32 + lc];
            __syncthreads();
            #pragma unroll
            for (int kk = 0; kk < 32; ++kk) {
                float b0 = Bs[kk][tx * 2], b1v = Bs[kk][tx * 2 + 1];
                float x0 = As[ty * 2][kk], x1 = As[ty * 2 + 1][kk];
                a00 += x0 * b0; a01 += x0 * b1v;
                a10 += x1 * b0; a11 += x1 * b1v;
            }
            __syncthreads();
        }
        int r0 = by * 32 + ty * 2, c0 = bx * 32 + tx * 2;
        if (r0 < 490)     { Bmat[(size_t)r0 * 512 + c0] = a00; Bmat[(size_t)r0 * 512 + c0 + 1] = a01; }
        if (r0 + 1 < 490) { Bmat[(size_t)(r0 + 1) * 512 + c0] = a10; Bmat[(size_t)(r0 + 1) * 512 + c0 + 1] = a11; }
    } else {
        int t = blk - 256;             // 0..79
        int k = t >> 3, b8 = t & 7;
        const float* wh = (k < 2) ? (w_note + k * 25088) : (w_reg + (k - 2) * 25088);
        float s = 0.f;
        for (int i = b8 * 256 + tid; i < 25088; i += 2048) s += wh[i] * vv[i / 49];
        __shared__ float red[256];
        red[tid] = s;
        __syncthreads();
        for (int off = 128; off; off >>= 1) {
            if (tid < off) red[tid] += red[tid + off];
            __syncthreads();
        }
        if (tid == 0) dpart[k * 8 + b8] = red[0];
    }
}

// ---------- fused main v2: Bmat-in-regs, lgkm-only barriers, 2-deep prefetch
__global__ __launch_bounds__(256) void k_mainf(const float* __restrict__ proj,
                                               const float* __restrict__ Bmat,
                                               float* __restrict__ part) {
    __shared__ float X[2][16][197];   // 25,216 B
    int b = blockIdx.x;               // 0..1023
    int g = b & 31;                   // channel group (16 ch)
    int n0 = (b >> 5) << 4;           // 16 n per block
    int tid = threadIdx.x;
    int wv = tid >> 6, lane = tid & 63;

    // chunk-invariant scatter coords: i = tid + s*256 = cc*49 + q
    int cc0 = tid / 49, q0 = tid - cc0 * 49;
    int cc1 = cc0 + 5, q1 = q0 + 11; if (q1 >= 49) { q1 -= 49; ++cc1; }
    int cc2 = cc1 + 5, q2 = q1 + 11; if (q2 >= 49) { q2 -= 49; ++cc2; }

    // chunk-invariant bilinear coords + Bmat register preload (40 floats)
    const float base = STEP * 0.5f - 0.5f;
    int i00s[4];
    float wxs[4], wys[4];
    float Bm[4][10];
    #pragma unroll
    for (int s = 0; s < 4; ++s) {
        int o = tid + s * 256; if (o > 783) o = 783;
        int ji = o >> 4, cl = o & 15;
        int j = (ji * 37) >> 8;
        int i2 = ji - j * 7;
        float yv = base + j * STEP;
        float xv = base + i2 * STEP;
        float y0f = floorf(yv), x0f = floorf(xv);
        wys[s] = yv - y0f; wxs[s] = xv - x0f;
        i00s[s] = cl * 197 + (int)y0f * 14 + (int)x0f;
        int bidx = (ji << 9) + (g << 4) + cl;
        #pragma unroll
        for (int k = 0; k < 10; ++k) Bm[s][k] = Bmat[(size_t)k * 25088 + bidx];
    }

    const float4* src = (const float4*)proj + (size_t)n0 * CHW4 + g * 784;

#define ISSUE(T, R0, R1, R2, R3) do { \
    const float4* sn_ = src + (size_t)(T) * CHW4; \
    R0 = sn_[tid]; R1 = sn_[tid + 256]; R2 = sn_[tid + 512]; \
    if (tid < 16) R3 = sn_[tid + 768]; \
} while (0)

#define SCATTER(BUF, R0, R1, R2, R3) do { \
    float* xw_ = &X[BUF][0][0]; \
    *(float4*)&xw_[cc0 * 197 + q0 * 4] = R0; \
    *(float4*)&xw_[cc1 * 197 + q1 * 4] = R1; \
    *(float4*)&xw_[cc2 * 197 + q2 * 4] = R2; \
    if (tid < 16) *(float4*)&xw_[15 * 197 + (tid + 33) * 4] = R3; \
} while (0)

#define COMPUTE_STORE(T, BUF) do { \
    const float* xb_ = &X[BUF][0][0]; \
    float acc[10]; \
    _Pragma("unroll") for (int k = 0; k < 10; ++k) acc[k] = 0.f; \
    _Pragma("unroll") for (int s = 0; s < 3; ++s) { \
        int i00 = i00s[s]; \
        float v00 = xb_[i00],      v01 = xb_[i00 + 1]; \
        float v10 = xb_[i00 + 14], v11 = xb_[i00 + 15]; \
        float top = v00 + (v01 - v00) * wxs[s]; \
        float bot = v10 + (v11 - v10) * wxs[s]; \
        float v = top + (bot - top) * wys[s]; \
        _Pragma("unroll") for (int k = 0; k < 10; ++k) acc[k] += v * Bm[s][k]; \
    } \
    if (tid < 16) { \
        int i00 = i00s[3]; \
        float v00 = xb_[i00],      v01 = xb_[i00 + 1]; \
        float v10 = xb_[i00 + 14], v11 = xb_[i00 + 15]; \
        float top = v00 + (v01 - v00) * wxs[3]; \
        float bot = v10 + (v11 - v10) * wxs[3]; \
        float v = top + (bot - top) * wys[3]; \
        _Pragma("unroll") for (int k = 0; k < 10; ++k) acc[k] += v * Bm[3][k]; \
    } \
    _Pragma("unroll") for (int k = 0; k < 10; ++k) { \
        float v = acc[k]; \
        v += __shfl_xor(v, 1);  v += __shfl_xor(v, 2);  v += __shfl_xor(v, 4); \
        v += __shfl_xor(v, 8);  v += __shfl_xor(v, 16); v += __shfl_xor(v, 32); \
        if (lane == k) \
            part[(((size_t)(n0 + (T)) * 32 + g) * 4 + wv) * 10 + k] = v; \
    } \
} while (0)

    float4 A0, A1, A2, A3, B0, B1, B2, B3;
    // prologue: chunks 0,1 in flight; chunk0 staged
    ISSUE(0, A0, A1, A2, A3);
    ISSUE(1, B0, B1, B2, B3);
    SCATTER(0, A0, A1, A2, A3);
    BAR();

    #pragma unroll 1
    for (int tt = 0; tt < 7; ++tt) {
        int t0 = tt * 2;
        // even iter: issue t0+2 -> A, scatter t0+1 (B) -> X[1], compute t0 from X[0]
        ISSUE(t0 + 2, A0, A1, A2, A3);
        SCATTER(1, B0, B1, B2, B3);
        COMPUTE_STORE(t0, 0);
        BAR();
        // odd iter: issue t0+3 -> B, scatter t0+2 (A) -> X[0], compute t0+1 from X[1]
        ISSUE(t0 + 3, B0, B1, B2, B3);
        SCATTER(0, A0, A1, A2, A3);
        COMPUTE_STORE(t0 + 1, 1);
        BAR();
    }
    // epilogue: chunks 14,15
    SCATTER(1, B0, B1, B2, B3);
    COMPUTE_STORE(14, 0);
    BAR();
    COMPUTE_STORE(15, 1);

#undef ISSUE
#undef SCATTER
#undef COMPUTE_STORE
}

// out[n,k] = bias + dpart-sum + 128 wave-partials (32 g x 4 wv)
__global__ void k_reduce(const float* __restrict__ part,
                         const float* __restrict__ dpart,
                         const float* __restrict__ b_note, const float* __restrict__ b_reg,
                         float* __restrict__ out) {
    int idx = blockIdx.x * 256 + threadIdx.x;  // 0..5119
    int n = idx / 10, k = idx % 10;
    float s = (k < 2) ? b_note[k] : b_reg[k - 2];
    for (int b = 0; b < 8; ++b) s += dpart[k * 8 + b];
    for (int w = 0; w < 128; ++w) s += part[((size_t)n * 128 + w) * 10 + k];
    if (k < 2) out[n * 2 + k] = s;
    else       out[1024 + n * 8 + (k - 2)] = s;
}

extern "C" void kernel_launch(void* const* d_in, const int* in_sizes, int n_in,
                              void* d_out, int out_size, void* d_ws, size_t ws_size,
                              hipStream_t stream) {
    const float* proj   = (const float*)d_in[0];
    const float* w1     = (const float*)d_in[1];
    const float* b1     = (const float*)d_in[2];
    const float* w2     = (const float*)d_in[3];
    const float* b2     = (const float*)d_in[4];
    const float* w3     = (const float*)d_in[5];
    const float* b3     = (const float*)d_in[6];
    const float* w_note = (const float*)d_in[7];
    const float* b_note = (const float*)d_in[8];
    const float* w_reg  = (const float*)d_in[9];
    const float* b_reg  = (const float*)d_in[10];

    float* ws    = (float*)d_ws;
    float* WH    = ws;
    float* Y     = WH + 250880;
    float* T1    = Y + 262144;
    float* Bmat  = T1 + 250880;
    float* u2    = Bmat + 250880;
    float* vv    = u2 + 512;
    float* dpart = vv + 512;
    float* part  = dpart + 80;
    float* out   = (float*)d_out;

    k_prep1<<<554, 512, 0, stream>>>(w_note, w_reg, w2, b1, b2, WH, u2);
    k_prep2<<<640, 256, 0, stream>>>(w1, w2, w3, WH, u2, b3, Y, T1, vv);
    k_prep3<<<336, 256, 0, stream>>>(T1, Y, w_note, w_reg, vv, Bmat, dpart);
    k_mainf<<<1024, 256, 0, stream>>>(proj, Bmat, part);
    k_reduce<<<20, 256, 0, stream>>>(part, dpart, b_note, b_reg, out);
}

// Round 18
// 100.154 us; speedup vs baseline: 1.2642x; 1.2642x over previous
//
#include <hip/hip_runtime.h>

// out[n,k] = d[k] + sum_{ji,c} Bt[ji*512+c][k] * bilinear_ji(proj[n,c,:,:])
// Bt = transpose of WH·(w3·w2·w1), k-major padded to 12 -> 3x float4 per slot.
//
// k_mainf = round-16 winner (95.4us total) + transposed Bmat coefficient
// loads: 30 scalar 100KB-strided gathers per thread-chunk -> 9 contiguous
// float4 loads. Same decomposition: block (n, half), 16 chunks of 16
// channels, contiguous 200KB walk, double-buffered LDS, 1-deep prefetch.
//
// ws layout (floats):
//   WH    [490][512]     off 0
//   Y     [512][512]     off 250880
//   T1    [490][512]     off 513024
//   Bt    [25088][12]    off 763904   (k-major, 10 used + 2 pad)
//   u2    [512]          off 1064960
//   vv    [512]          off 1065472
//   dpart [10][8]        off 1065984
//   part  [1024*4][10]   off 1066064

#define CHW4 25088   // float4 per proj row
#define STEP 1.8571428571428572f  // 13/7

// ---------- prep level 1: WH transpose (blocks 0..489) + u2=b2+w2*b1 (490..553)
__global__ __launch_bounds__(512) void k_prep1(
    const float* __restrict__ w_note, const float* __restrict__ w_reg,
    const float* __restrict__ w2, const float* __restrict__ b1,
    const float* __restrict__ b2,
    float* __restrict__ WH, float* __restrict__ u2) {
    int blk = blockIdx.x;
    int tid = threadIdx.x;
    if (blk < 490) {
        int k = blk / 49, ji = blk % 49;
        const float* wh = (k < 2) ? (w_note + k * 25088) : (w_reg + (k - 2) * 25088);
        WH[(size_t)blk * 512 + tid] = wh[tid * 49 + ji];
    } else {
        int wv = tid >> 6, lane = tid & 63;
        int o = (blk - 490) * 8 + wv;
        float s = 0.f;
        #pragma unroll
        for (int r = 0; r < 8; ++r) s += w2[(size_t)o * 512 + lane + r * 64] * b1[lane + r * 64];
        for (int off = 32; off; off >>= 1) s += __shfl_down(s, off);
        if (lane == 0) u2[o] = b2[o] + s;
    }
}

// ---------- prep level 2: {Y=w2*w1 | T1=WH*w3} (0..511) + vv=b3+w3*u2 (512..639)
__global__ __launch_bounds__(256) void k_prep2(
    const float* __restrict__ w1, const float* __restrict__ w2,
    const float* __restrict__ w3, const float* __restrict__ WH,
    const float* __restrict__ u2, const float* __restrict__ b3,
    float* __restrict__ Y, float* __restrict__ T1, float* __restrict__ vv) {
    int blk = blockIdx.x;
    int tid = threadIdx.x;
    if (blk < 512) {
        __shared__ float As[32][36];
        __shared__ float Bs[32][36];
        const float* A; const float* B; float* C; int M;
        if (blk < 256) { A = w2; B = w1; C = Y;  M = 512; }
        else           { A = WH; B = w3; C = T1; M = 490; }
        int t = blk & 255;
        int bx = t & 15, by = t >> 4;
        int lr = tid >> 3, lc = (tid & 7) << 2;
        int tx = tid & 15, ty = tid >> 4;
        float a00 = 0.f, a01 = 0.f, a10 = 0.f, a11 = 0.f;
        for (int kc = 0; kc < 512; kc += 32) {
            int gr = by * 32 + lr;
            float4 av = make_float4(0.f, 0.f, 0.f, 0.f);
            if (gr < M) av = *(const float4*)&A[(size_t)gr * 512 + kc + lc];
            *(float4*)&As[lr][lc] = av;
            *(float4*)&Bs[lr][lc] = *(const float4*)&B[(size_t)(kc + lr) * 512 + bx * 32 + lc];
            __syncthreads();
            #pragma unroll
            for (int kk = 0; kk < 32; ++kk) {
                float b0 = Bs[kk][tx * 2], b1v = Bs[kk][tx * 2 + 1];
                float x0 = As[ty * 2][kk], x1 = As[ty * 2 + 1][kk];
                a00 += x0 * b0; a01 += x0 * b1v;
                a10 += x1 * b0; a11 += x1 * b1v;
            }
            __syncthreads();
        }
        int r0 = by * 32 + ty * 2, c0 = bx * 32 + tx * 2;
        if (r0 < M)     { C[(size_t)r0 * 512 + c0] = a00; C[(size_t)r0 * 512 + c0 + 1] = a01; }
        if (r0 + 1 < M) { C[(size_t)(r0 + 1) * 512 + c0] = a10; C[(size_t)(r0 + 1) * 512 + c0 + 1] = a11; }
    } else {
        int wv = tid >> 6, lane = tid & 63;
        int o = (blk - 512) * 4 + wv;
        float s = 0.f;
        #pragma unroll
        for (int r = 0; r < 8; ++r) s += w3[(size_t)o * 512 + lane + r * 64] * u2[lane + r * 64];
        for (int off = 32; off; off >>= 1) s += __shfl_down(s, off);
        if (lane == 0) vv[o] = b3[o] + s;
    }
}

// ---------- prep level 3: Bt = transpose(T1*Y) k-major (0..255) + dpart (256..335)
__global__ __launch_bounds__(256) void k_prep3(
    const float* __restrict__ T1, const float* __restrict__ Y,
    const float* __restrict__ w_note, const float* __restrict__ w_reg,
    const float* __restrict__ vv,
    float* __restrict__ Bt, float* __restrict__ dpart) {
    int blk = blockIdx.x;
    int tid = threadIdx.x;
    if (blk < 256) {
        __shared__ float As[32][36];
        __shared__ float Bs[32][36];
        int bx = blk & 15, by = blk >> 4;
        int lr = tid >> 3, lc = (tid & 7) << 2;
        int tx = tid & 15, ty = tid >> 4;
        int gr = by * 32 + lr;
        float a00 = 0.f, a01 = 0.f, a10 = 0.f, a11 = 0.f;
        for (int kc = 0; kc < 512; kc += 32) {
            float4 av = make_float4(0.f, 0.f, 0.f, 0.f);
            if (gr < 490) av = *(const float4*)&T1[(size_t)gr * 512 + kc + lc];
            *(float4*)&As[lr][lc] = av;
            *(float4*)&Bs[lr][lc] = *(const float4*)&Y[(size_t)(kc + lr) * 512 + bx * 32 + lc];
            __syncthreads();
            #pragma unroll
            for (int kk = 0; kk < 32; ++kk) {
                float b0 = Bs[kk][tx * 2], b1v = Bs[kk][tx * 2 + 1];
                float x0 = As[ty * 2][kk], x1 = As[ty * 2 + 1][kk];
                a00 += x0 * b0; a01 += x0 * b1v;
                a10 += x1 * b0; a11 += x1 * b1v;
            }
            __syncthreads();
        }
        int r0 = by * 32 + ty * 2, c0 = bx * 32 + tx * 2;
        if (r0 < 490) {
            int k = r0 / 49, ji = r0 - k * 49;
            Bt[((size_t)(ji * 512 + c0)) * 12 + k] = a00;
            Bt[((size_t)(ji * 512 + c0 + 1)) * 12 + k] = a01;
        }
        if (r0 + 1 < 490) {
            int k = (r0 + 1) / 49, ji = (r0 + 1) - k * 49;
            Bt[((size_t)(ji * 512 + c0)) * 12 + k] = a10;
            Bt[((size_t)(ji * 512 + c0 + 1)) * 12 + k] = a11;
        }
    } else {
        int t = blk - 256;             // 0..79
        int k = t >> 3, b8 = t & 7;
        const float* wh = (k < 2) ? (w_note + k * 25088) : (w_reg + (k - 2) * 25088);
        float s = 0.f;
        for (int i = b8 * 256 + tid; i < 25088; i += 2048) s += wh[i] * vv[i / 49];
        __shared__ float red[256];
        red[tid] = s;
        __syncthreads();
        for (int off = 128; off; off >>= 1) {
            if (tid < off) red[tid] += red[tid + off];
            __syncthreads();
        }
        if (tid == 0) dpart[k * 8 + b8] = red[0];
    }
}

// ---------- fused main (round-16 structure + Bt wide coefficient loads)
__global__ __launch_bounds__(256) void k_mainf(const float* __restrict__ proj,
                                               const float* __restrict__ Bt,
                                               float* __restrict__ part) {
    __shared__ float X[2][16][197];   // 25,216 B
    int b = blockIdx.x;               // 0..1023
    int n = b >> 1;
    int ch0 = (b & 1) << 4;           // chunk index base: ch = ch0 + t
    int tid = threadIdx.x;
    int wv = tid >> 6, lane = tid & 63;

    // chunk-invariant staging scatter coords: i = tid + s*256 = cc*49 + q
    int cc0 = tid / 49,            q0 = tid - (tid / 49) * 49;
    int cc1 = cc0 + 5,             q1 = q0 + 11; if (q1 >= 49) { q1 -= 49; ++cc1; }
    int cc2 = cc1 + 5,             q2 = q1 + 11; if (q2 >= 49) { q2 -= 49; ++cc2; }

    // chunk-invariant bilinear coords + Bt slot base offsets
    const float base = STEP * 0.5f - 0.5f;
    int   i00s[4];
    float wxs[4], wys[4];
    size_t boff[4];
    #pragma unroll
    for (int s = 0; s < 4; ++s) {
        int o = tid + s * 256;
        if (o > 783) o = 783;          // dummy for inactive tail lanes
        int ji = o >> 4, cl = o & 15;
        int j = (ji * 37) >> 8;        // floor(ji/7) for ji<49
        int i2 = ji - j * 7;
        float yv = base + j * STEP;
        float xv = base + i2 * STEP;
        float y0f = floorf(yv), x0f = floorf(xv);
        wys[s] = yv - y0f; wxs[s] = xv - x0f;
        i00s[s] = cl * 197 + (int)y0f * 14 + (int)x0f;
        boff[s] = ((size_t)(ji << 9) + (ch0 << 4) + cl) * 12;  // + t*192 at use
    }

    const float4* src0 = (const float4*)proj + (size_t)n * CHW4 + ch0 * 784;
    float acc[10];
    #pragma unroll
    for (int k = 0; k < 10; ++k) acc[k] = 0.f;

    // prologue: stage chunk 0 into buf 0
    {
        float4 v0 = src0[tid];
        float4 v1 = src0[tid + 256];
        float4 v2 = src0[tid + 512];
        float* xb = &X[0][0][0];
        *(float4*)&xb[cc0 * 197 + q0 * 4] = v0;
        *(float4*)&xb[cc1 * 197 + q1 * 4] = v1;
        *(float4*)&xb[cc2 * 197 + q2 * 4] = v2;
        if (tid < 16) *(float4*)&xb[15 * 197 + (tid + 33) * 4] = src0[tid + 768];
    }
    __syncthreads();

    int cur = 0;
    #pragma unroll 1
    for (int t = 0; t < 16; ++t) {
        // issue next chunk's loads early
        float4 v0, v1, v2, v3;
        if (t < 15) {
            const float4* sn = src0 + (t + 1) * 784;
            v0 = sn[tid]; v1 = sn[tid + 256]; v2 = sn[tid + 512];
            if (tid < 16) v3 = sn[tid + 768];
        }
        // compute current chunk: bilinear from LDS, coeffs = 3x float4 from Bt
        const float* xb = &X[cur][0][0];
        size_t tof = (size_t)t * 192;
        #pragma unroll
        for (int s = 0; s < 3; ++s) {
            int i00 = i00s[s];
            float v00 = xb[i00],      v01 = xb[i00 + 1];
            float v10 = xb[i00 + 14], v11 = xb[i00 + 15];
            float top = v00 + (v01 - v00) * wxs[s];
            float bot = v10 + (v11 - v10) * wxs[s];
            float v = top + (bot - top) * wys[s];
            const float* bp = Bt + boff[s] + tof;
            float4 c0 = *(const float4*)bp;
            float4 c1 = *(const float4*)(bp + 4);
            float2 c2 = *(const float2*)(bp + 8);
            acc[0] += v * c0.x; acc[1] += v * c0.y; acc[2] += v * c0.z; acc[3] += v * c0.w;
            acc[4] += v * c1.x; acc[5] += v * c1.y; acc[6] += v * c1.z; acc[7] += v * c1.w;
            acc[8] += v * c2.x; acc[9] += v * c2.y;
        }
        if (tid < 16) {
            int i00 = i00s[3];
            float v00 = xb[i00],      v01 = xb[i00 + 1];
            float v10 = xb[i00 + 14], v11 = xb[i00 + 15];
            float top = v00 + (v01 - v00) * wxs[3];
            float bot = v10 + (v11 - v10) * wxs[3];
            float v = top + (bot - top) * wys[3];
            const float* bp = Bt + boff[3] + tof;
            float4 c0 = *(const float4*)bp;
            float4 c1 = *(const float4*)(bp + 4);
            float2 c2 = *(const float2*)(bp + 8);
            acc[0] += v * c0.x; acc[1] += v * c0.y; acc[2] += v * c0.z; acc[3] += v * c0.w;
            acc[4] += v * c1.x; acc[5] += v * c1.y; acc[6] += v * c1.z; acc[7] += v * c1.w;
            acc[8] += v * c2.x; acc[9] += v * c2.y;
        }
        // scatter next chunk into the other buffer
        if (t < 15) {
            float* xw = &X[cur ^ 1][0][0];
            *(float4*)&xw[cc0 * 197 + q0 * 4] = v0;
            *(float4*)&xw[cc1 * 197 + q1 * 4] = v1;
            *(float4*)&xw[cc2 * 197 + q2 * 4] = v2;
            if (tid < 16) *(float4*)&xw[15 * 197 + (tid + 33) * 4] = v3;
        }
        __syncthreads();
        cur ^= 1;
    }

    #pragma unroll
    for (int k = 0; k < 10; ++k) {
        float v = acc[k];
        v += __shfl_xor(v, 1);
        v += __shfl_xor(v, 2);
        v += __shfl_xor(v, 4);
        v += __shfl_xor(v, 8);
        v += __shfl_xor(v, 16);
        v += __shfl_xor(v, 32);
        if (lane == k) part[((size_t)b * 4 + wv) * 10 + k] = v;
    }
}

// out[n,k] = bias + dpart-sum + 8 wave-partials (2 halves x 4 waves)
__global__ void k_reduce(const float* __restrict__ part,
                         const float* __restrict__ dpart,
                         const float* __restrict__ b_note, const float* __restrict__ b_reg,
                         float* __restrict__ out) {
    int idx = blockIdx.x * 256 + threadIdx.x;  // 0..5119
    int n = idx / 10, k = idx % 10;
    float s = (k < 2) ? b_note[k] : b_reg[k - 2];
    for (int b = 0; b < 8; ++b) s += dpart[k * 8 + b];
    #pragma unroll
    for (int h = 0; h < 2; ++h)
        for (int w = 0; w < 4; ++w)
            s += part[(((size_t)(n * 2 + h)) * 4 + w) * 10 + k];
    if (k < 2) out[n * 2 + k] = s;
    else       out[1024 + n * 8 + (k - 2)] = s;
}

extern "C" void kernel_launch(void* const* d_in, const int* in_sizes, int n_in,
                              void* d_out, int out_size, void* d_ws, size_t ws_size,
                              hipStream_t stream) {
    const float* proj   = (const float*)d_in[0];
    const float* w1     = (const float*)d_in[1];
    const float* b1     = (const float*)d_in[2];
    const float* w2     = (const float*)d_in[3];
    const float* b2     = (const float*)d_in[4];
    const float* w3     = (const float*)d_in[5];
    const float* b3     = (const float*)d_in[6];
    const float* w_note = (const float*)d_in[7];
    const float* b_note = (const float*)d_in[8];
    const float* w_reg  = (const float*)d_in[9];
    const float* b_reg  = (const float*)d_in[10];

    float* ws    = (float*)d_ws;
    float* WH    = ws;
    float* Y     = WH + 250880;
    float* T1    = Y + 262144;
    float* Bt    = T1 + 250880;
    float* u2    = Bt + 301056;
    float* vv    = u2 + 512;
    float* dpart = vv + 512;
    float* part  = dpart + 80;
    float* out   = (float*)d_out;

    k_prep1<<<554, 512, 0, stream>>>(w_note, w_reg, w2, b1, b2, WH, u2);
    k_prep2<<<640, 256, 0, stream>>>(w1, w2, w3, WH, u2, b3, Y, T1, vv);
    k_prep3<<<336, 256, 0, stream>>>(T1, Y, w_note, w_reg, vv, Bt, dpart);
    k_mainf<<<1024, 256, 0, stream>>>(proj, Bt, part);
    k_reduce<<<20, 256, 0, stream>>>(part, dpart, b_note, b_reg, out);
}